// Round 1
// baseline (29486.368 us; speedup 1.0000x reference)
//
#include <hip/hip_runtime.h>
#include <cmath>

#define HW 128
#define NPIX (HW * HW)

__device__ __forceinline__ float sigmoidf_(float x) {
    return 1.0f / (1.0f + expf(-x));
}

// Fused ConvLSTM cell: for hidden channel d (= blockIdx.y), compute the four
// gate conv outputs (channels d, d+64, d+128, d+192 of the 256-channel conv),
// then the LSTM elementwise update. Input = concat(xa [CIN_A ch], xb [64 ch]).
// Block: 64 threads, tile 16 rows x 32 cols, each thread 2x4 pixels.
template<int CIN_A, int CIN>
__global__ __launch_bounds__(64)
void cell_kernel(const float* __restrict__ xa, const float* __restrict__ xb,
                 const float* __restrict__ W,  const float* __restrict__ bias,
                 const float* __restrict__ c_prev,
                 float* __restrict__ h_out, float* __restrict__ c_out)
{
    __shared__ float in_lds[4][18][35];   // 4 in-ch chunk, 18 rows, 34 cols (+1 pad)

    const int tid = threadIdx.x;
    const int sp  = blockIdx.x;           // 0..31 : 8 row-tiles x 4 col-tiles
    const int ty  = sp >> 2, tx = sp & 3;
    const int y0  = ty * 16, x0 = tx * 32;
    const int d   = blockIdx.y;           // hidden channel 0..63
    const int r0  = (tid >> 3) * 2;       // thread's first row in tile (0..14)
    const int p0  = (tid & 7) * 4;        // thread's first col in tile (0..28)

    float acc[4][2][4];
    #pragma unroll
    for (int g = 0; g < 4; ++g)
        #pragma unroll
        for (int rr = 0; rr < 2; ++rr)
            #pragma unroll
            for (int cc = 0; cc < 4; ++cc) acc[g][rr][cc] = 0.0f;

    for (int cb = 0; cb < CIN; cb += 4) {
        // ---- stage 4 x 18 x 34 input patch (zero-padded at image borders) ----
        for (int i = tid; i < 4 * 18 * 34; i += 64) {
            int c   = i / (18 * 34);
            int rem = i - c * (18 * 34);
            int iy  = rem / 34;
            int ix  = rem - iy * 34;
            int gy  = y0 - 1 + iy, gx = x0 - 1 + ix;
            float v = 0.0f;
            if (gy >= 0 && gy < HW && gx >= 0 && gx < HW) {
                int cg = cb + c;
                const float* src;
                int cl;
                if (cg < CIN_A) { src = xa; cl = cg; }
                else            { src = xb; cl = cg - CIN_A; }
                v = src[(size_t)cl * NPIX + gy * HW + gx];
            }
            in_lds[c][iy][ix] = v;
        }
        __syncthreads();

        // ---- compute: 4 input channels x 4 gates x (2x4 px) x 9 taps ----
        #pragma unroll
        for (int ci = 0; ci < 4; ++ci) {
            float in_r[4][6];
            #pragma unroll
            for (int dy = 0; dy < 4; ++dy)
                #pragma unroll
                for (int j = 0; j < 6; ++j)
                    in_r[dy][j] = in_lds[ci][r0 + dy][p0 + j];

            #pragma unroll
            for (int g = 0; g < 4; ++g) {
                const int och = (g << 6) + d;
                int wb = (och * CIN + cb + ci) * 9;
                wb = __builtin_amdgcn_readfirstlane(wb);  // force SGPR/scalar loads
                float w[9];
                #pragma unroll
                for (int k = 0; k < 9; ++k) w[k] = W[wb + k];

                #pragma unroll
                for (int rr = 0; rr < 2; ++rr)
                    #pragma unroll
                    for (int cc = 0; cc < 4; ++cc) {
                        float s = acc[g][rr][cc];
                        #pragma unroll
                        for (int ky = 0; ky < 3; ++ky)
                            #pragma unroll
                            for (int kx = 0; kx < 3; ++kx)
                                s += w[ky * 3 + kx] * in_r[rr + ky][cc + kx];
                        acc[g][rr][cc] = s;
                    }
            }
        }
        __syncthreads();
    }

    // ---- LSTM elementwise epilogue ----
    const float b_i = bias[d];
    const float b_f = bias[64 + d];
    const float b_o = bias[128 + d];
    const float b_g = bias[192 + d];

    #pragma unroll
    for (int rr = 0; rr < 2; ++rr) {
        const int gy = y0 + r0 + rr;
        const size_t off = (size_t)d * NPIX + gy * HW + (x0 + p0);
        float4 cp = *reinterpret_cast<const float4*>(&c_prev[off]);
        float cin[4] = {cp.x, cp.y, cp.z, cp.w};
        float cn[4], hn[4];
        #pragma unroll
        for (int cc = 0; cc < 4; ++cc) {
            float ig = sigmoidf_(acc[0][rr][cc] + b_i);
            float fg = sigmoidf_(acc[1][rr][cc] + b_f);
            float og = sigmoidf_(acc[2][rr][cc] + b_o);
            float gg = tanhf(acc[3][rr][cc] + b_g);
            float c2 = fg * cin[cc] + ig * gg;
            cn[cc] = c2;
            hn[cc] = og * tanhf(c2);
        }
        *reinterpret_cast<float4*>(&c_out[off]) = make_float4(cn[0], cn[1], cn[2], cn[3]);
        *reinterpret_cast<float4*>(&h_out[off]) = make_float4(hn[0], hn[1], hn[2], hn[3]);
    }
}

// Readout conv: 64 -> 1 channels, 3x3 SAME. Grid 64 blocks (8x8 tiles of 16x16),
// 256 threads, one pixel per thread.
__global__ __launch_bounds__(256)
void readout_kernel(const float* __restrict__ h1, const float* __restrict__ Wr,
                    const float* __restrict__ br, float* __restrict__ y)
{
    __shared__ float t_lds[8][18][19];
    const int tid = threadIdx.x;
    const int bx  = blockIdx.x;          // 0..63
    const int ty  = bx >> 3, tx = bx & 7;
    const int y0  = ty * 16, x0 = tx * 16;
    const int r   = tid >> 4, p = tid & 15;

    float s = br[0];
    for (int db = 0; db < 64; db += 8) {
        for (int i = tid; i < 8 * 18 * 18; i += 256) {
            int c   = i / 324;
            int rem = i - c * 324;
            int iy  = rem / 18, ix = rem - iy * 18;
            int gy  = y0 - 1 + iy, gx = x0 - 1 + ix;
            float v = 0.0f;
            if (gy >= 0 && gy < HW && gx >= 0 && gx < HW)
                v = h1[(size_t)(db + c) * NPIX + gy * HW + gx];
            t_lds[c][iy][ix] = v;
        }
        __syncthreads();
        #pragma unroll
        for (int c = 0; c < 8; ++c) {
            int wb = __builtin_amdgcn_readfirstlane((db + c) * 9);
            #pragma unroll
            for (int ky = 0; ky < 3; ++ky)
                #pragma unroll
                for (int kx = 0; kx < 3; ++kx)
                    s += Wr[wb + ky * 3 + kx] * t_lds[c][r + ky][p + kx];
        }
        __syncthreads();
    }
    y[(y0 + r) * HW + (x0 + p)] = s;
}

extern "C" void kernel_launch(void* const* d_in, const int* in_sizes, int n_in,
                              void* d_out, int out_size, void* d_ws, size_t ws_size,
                              hipStream_t stream)
{
    const float* x  = (const float*)d_in[0];   // [1,32,4,128,128]
    const float* W0 = (const float*)d_in[1];   // [256,68,3,3]
    const float* b0 = (const float*)d_in[2];   // [256]
    const float* W1 = (const float*)d_in[3];   // [256,128,3,3]
    const float* b1 = (const float*)d_in[4];   // [256]
    const float* Wr = (const float*)d_in[5];   // [1,64,3,3]
    const float* br = (const float*)d_in[6];   // [1]
    float* y = (float*)d_out;                  // [32,1,128,128]

    float* ws = (float*)d_ws;
    const size_t HC = (size_t)64 * NPIX;       // one state buffer: 1M floats
    float* h0a = ws + 0 * HC;
    float* h0b = ws + 1 * HC;
    float* c0  = ws + 2 * HC;
    float* h1a = ws + 3 * HC;
    float* h1b = ws + 4 * HC;
    float* c1  = ws + 5 * HC;

    // zero-init all recurrent state (h0, c0, h1, c1 start at zeros)
    hipMemsetAsync(d_ws, 0, 6 * HC * sizeof(float), stream);

    dim3 cgrid(32, 64);
    for (int t = 0; t < 32; ++t) {
        const float* xt = x + (size_t)t * 4 * NPIX;
        const float* h0_rd = (t & 1) ? h0b : h0a;
        float*       h0_wr = (t & 1) ? h0a : h0b;
        const float* h1_rd = (t & 1) ? h1b : h1a;
        float*       h1_wr = (t & 1) ? h1a : h1b;

        cell_kernel<4, 68><<<cgrid, 64, 0, stream>>>(xt, h0_rd, W0, b0, c0, h0_wr, c0);
        cell_kernel<64, 128><<<cgrid, 64, 0, stream>>>(h0_wr, h1_rd, W1, b1, c1, h1_wr, c1);
        readout_kernel<<<64, 256, 0, stream>>>(h1_wr, Wr, br, y + (size_t)t * NPIX);
    }
}

// Round 2
// 1839.212 us; speedup vs baseline: 16.0321x; 16.0321x over previous
//
#include <hip/hip_runtime.h>
#include <cstdint>
#include <cmath>

#define HW 128
#define NPIX (HW * HW)

typedef _Float16 half8 __attribute__((ext_vector_type(8)));
typedef _Float16 half4 __attribute__((ext_vector_type(4)));
typedef float floatx16 __attribute__((ext_vector_type(16)));

__device__ __forceinline__ float sigf(float x) { return 1.0f / (1.0f + expf(-x)); }

// ---------------------------------------------------------------------------
// Fused ConvLSTM cell via implicit GEMM on v_mfma_f32_32x32x16_f16.
//   M = 256 gate rows (packed: mf = hg*2+f, frag rows rr: gate = f*2+(rr>>4),
//       hid = hg*16 + (rr&15)),  N = pixels,  K = 16 in-ch per step, 9 taps.
//   Block: 256 thr = 4 waves, computes 128 gate rows (hg pair) x 128 px (8x16).
//   Wave: 64 rows x 64 px -> acc[2 mf][2 nf] of f32x16.
//   LDS: input tile [10 rows][18 cols][16 chunks of 8 fp16], chunk XOR-swizzled
//   by (col&15) -> 2-way banks on ds_read_b128 (free).
// ---------------------------------------------------------------------------
template<int NKC, bool CELL1>
__global__ __launch_bounds__(256)
void cell_mfma(const _Float16* __restrict__ srcA,   // cell1: xh_t [px][16]; cell2: h0 [px][64]
               const _Float16* __restrict__ srcB,   // h_prev of this cell [px][64]
               const _Float16* __restrict__ Wp,     // packed weights [9][NKC][8][512]
               const float* __restrict__ bias,      // [256]
               float* __restrict__ c_io,            // [px][64] fp32, in-place
               _Float16* __restrict__ h_out)        // [px][64] fp16
{
    __shared__ __align__(16) _Float16 lds[10 * 18 * 16 * 8];   // 46080 B

    const int tid = threadIdx.x;
    const int ty = blockIdx.x >> 3, tx = blockIdx.x & 7;
    const int y0 = ty * 8, x0 = tx * 16;

    // ---- stage input tile (halo 10x18, 16 ch-chunks, swizzled slot = chunk^(c&15)) ----
    for (int i = tid; i < 10 * 18 * 16; i += 256) {
        int r   = i / 288;                 // 288 = 18*16
        int rem = i - r * 288;
        int c   = rem >> 4;
        int ks  = rem & 15;
        int chunk = ks ^ (c & 15);
        int gy = y0 - 1 + r, gx = x0 - 1 + c;
        half8 v = {0, 0, 0, 0, 0, 0, 0, 0};
        if (gy >= 0 && gy < HW && gx >= 0 && gx < HW) {
            int px = gy * HW + gx;
            if (CELL1) {
                if (chunk < 2)       v = *(const half8*)(srcA + px * 16 + chunk * 8);
                else if (chunk < 10) v = *(const half8*)(srcB + px * 64 + (chunk - 2) * 8);
                // chunks 10-15: zero pad
            } else {
                if (chunk < 8) v = *(const half8*)(srcA + px * 64 + chunk * 8);
                else           v = *(const half8*)(srcB + px * 64 + (chunk - 8) * 8);
            }
        }
        *(half8*)(lds + (size_t)i * 8) = v;
    }
    __syncthreads();

    const int lane = tid & 63;
    const int w    = tid >> 6;
    const int l4   = (lane >> 4) & 1;
    const int l5   = lane >> 5;
    const int xc   = lane & 15;
    const int hg   = blockIdx.y * 2 + (w & 1);   // hid group 0..3
    const int ph   = w >> 1;                     // px half (rows 4*ph..4*ph+3)
    const int rb   = 4 * ph + l4;                // local halo row base

    floatx16 acc00 = {0,0,0,0,0,0,0,0,0,0,0,0,0,0,0,0};
    floatx16 acc10 = {0,0,0,0,0,0,0,0,0,0,0,0,0,0,0,0};
    floatx16 acc01 = {0,0,0,0,0,0,0,0,0,0,0,0,0,0,0,0};
    floatx16 acc11 = {0,0,0,0,0,0,0,0,0,0,0,0,0,0,0,0};

    for (int kc = 0; kc < NKC; ++kc) {
        #pragma unroll
        for (int tap = 0; tap < 9; ++tap) {
            const int dy = tap / 3, dx = tap % 3;
            const _Float16* ap = Wp + (((size_t)(tap * NKC + kc) * 8 + hg * 2) << 9) + (lane << 3);
            half8 a0 = *(const half8*)(ap);
            half8 a1 = *(const half8*)(ap + 512);
            int c_  = xc + dx;
            int ksl = ((kc << 1) | l5) ^ (c_ & 15);
            int r0_ = rb + dy;
            half8 b0 = *(const half8*)(lds + ((((r0_    ) * 18 + c_) * 16 + ksl) << 3));
            half8 b1 = *(const half8*)(lds + ((((r0_ + 2) * 18 + c_) * 16 + ksl) << 3));
            acc00 = __builtin_amdgcn_mfma_f32_32x32x16_f16(a0, b0, acc00, 0, 0, 0);
            acc10 = __builtin_amdgcn_mfma_f32_32x32x16_f16(a1, b0, acc10, 0, 0, 0);
            acc01 = __builtin_amdgcn_mfma_f32_32x32x16_f16(a0, b1, acc01, 0, 0, 0);
            acc11 = __builtin_amdgcn_mfma_f32_32x32x16_f16(a1, b1, acc11, 0, 0, 0);
        }
    }

    // ---- LSTM epilogue.  C/D: col = lane&31, row = (r&3)+8*(r>>2)+4*l5. ----
    const int gx = x0 + xc;
    #pragma unroll
    for (int n = 0; n < 2; ++n) {
        const floatx16& A0 = n ? acc01 : acc00;   // gates i (rows<16), f (rows>=16)
        const floatx16& A1 = n ? acc11 : acc10;   // gates o, g
        int gy = y0 + 4 * ph + 2 * n + l4;
        size_t pxo = (size_t)(gy * HW + gx) * 64;
        #pragma unroll
        for (int q = 0; q < 2; ++q) {
            int ch0 = hg * 16 + 4 * l5 + 8 * q;    // first of 4 hid channels
            float4 b_i4 = *(const float4*)(bias +       ch0);
            float4 b_f4 = *(const float4*)(bias +  64 + ch0);
            float4 b_o4 = *(const float4*)(bias + 128 + ch0);
            float4 b_g4 = *(const float4*)(bias + 192 + ch0);
            float bi[4] = {b_i4.x, b_i4.y, b_i4.z, b_i4.w};
            float bf[4] = {b_f4.x, b_f4.y, b_f4.z, b_f4.w};
            float bo[4] = {b_o4.x, b_o4.y, b_o4.z, b_o4.w};
            float bg[4] = {b_g4.x, b_g4.y, b_g4.z, b_g4.w};
            float4 cp4 = *(const float4*)(c_io + pxo + ch0);
            float cpv[4] = {cp4.x, cp4.y, cp4.z, cp4.w};
            float cn[4];
            half4 hn;
            #pragma unroll
            for (int lo = 0; lo < 4; ++lo) {
                int r0_ = 4 * q + lo;        // rows < 16  -> gates i / o
                int r1_ = 8 + 4 * q + lo;    // rows >= 16 -> gates f / g
                float iv = sigf(A0[r0_] + bi[lo]);
                float fv = sigf(A0[r1_] + bf[lo]);
                float ov = sigf(A1[r0_] + bo[lo]);
                float gv = tanhf(A1[r1_] + bg[lo]);
                float cv = fv * cpv[lo] + iv * gv;
                cn[lo] = cv;
                hn[lo] = (_Float16)(ov * tanhf(cv));
            }
            *(float4*)(c_io + pxo + ch0) = make_float4(cn[0], cn[1], cn[2], cn[3]);
            *(half4*)(h_out + pxo + ch0) = hn;
        }
    }
}

// ---------------------------------------------------------------------------
// Weight repack: W [256][CIN_W][3][3] fp32 -> Wp [9][NKC][8 mf][64 lanes][8] fp16.
// Logical k = kc*16 + (lane>>5)*8 + j must match the cell kernel's B chunk map.
// ---------------------------------------------------------------------------
__global__ void pack_w(const float* __restrict__ W, _Float16* __restrict__ Wp,
                       int NKC, int CIN_W, int cell1, int total)
{
    int idx = blockIdx.x * 256 + threadIdx.x;
    if (idx >= total) return;
    int j  = idx & 7;
    int l  = (idx >> 3) & 63;
    int mf = (idx >> 9) & 7;
    int tk = idx >> 12;                 // tap*NKC + kc
    int kc = tk % NKC, tap = tk / NKC;
    int rr = l & 31, l5 = l >> 5;
    int f = mf & 1, hg = mf >> 1;
    int gate = f * 2 + (rr >> 4);
    int hid  = hg * 16 + (rr & 15);
    int o = gate * 64 + hid;
    int k = kc * 16 + l5 * 8 + j;
    int cin;
    if (cell1) cin = (k < 4) ? k : ((k >= 16 && k < 80) ? (k - 12) : -1);
    else       cin = k;
    float v = (cin >= 0) ? W[((size_t)o * CIN_W + cin) * 9 + tap] : 0.0f;
    Wp[idx] = (_Float16)v;
}

// x [32][4][128][128] fp32 -> xh [32][px][16] fp16 (ch 0-3 real, 4-15 zero)
__global__ void xconv(const float* __restrict__ x, _Float16* __restrict__ xh)
{
    int idx = blockIdx.x * 256 + threadIdx.x;       // 524288
    int t = idx >> 14, px = idx & 16383;
    const float* xs = x + (size_t)t * 4 * NPIX + px;
    half8 v = {0, 0, 0, 0, 0, 0, 0, 0};
    v[0] = (_Float16)xs[0];
    v[1] = (_Float16)xs[NPIX];
    v[2] = (_Float16)xs[2 * NPIX];
    v[3] = (_Float16)xs[3 * NPIX];
    half8 z = {0, 0, 0, 0, 0, 0, 0, 0};
    *(half8*)(xh + (size_t)idx * 16)     = v;
    *(half8*)(xh + (size_t)idx * 16 + 8) = z;
}

// Readout conv 64->1, one px per thread; h1 is fp16 [px][64].
__global__ __launch_bounds__(256)
void readout(const _Float16* __restrict__ h1, const float* __restrict__ Wr,
             const float* __restrict__ br, float* __restrict__ y)
{
    __shared__ float wl[576];
    int tid = threadIdx.x;
    for (int i = tid; i < 576; i += 256) wl[i] = Wr[i];
    __syncthreads();
    int px = blockIdx.x * 256 + tid;
    int py = px >> 7, pxx = px & 127;
    float s = br[0];
    #pragma unroll
    for (int dy = -1; dy <= 1; ++dy) {
        int gy = py + dy;
        if (gy < 0 || gy >= HW) continue;
        #pragma unroll
        for (int dx = -1; dx <= 1; ++dx) {
            int gx = pxx + dx;
            if (gx < 0 || gx >= HW) continue;
            const _Float16* hp = h1 + (size_t)(gy * HW + gx) * 64;
            int tap = (dy + 1) * 3 + (dx + 1);
            #pragma unroll
            for (int dc = 0; dc < 64; dc += 8) {
                half8 hv = *(const half8*)(hp + dc);
                #pragma unroll
                for (int jj = 0; jj < 8; ++jj)
                    s += wl[(dc + jj) * 9 + tap] * (float)hv[jj];
            }
        }
    }
    y[px] = s;
}

extern "C" void kernel_launch(void* const* d_in, const int* in_sizes, int n_in,
                              void* d_out, int out_size, void* d_ws, size_t ws_size,
                              hipStream_t stream)
{
    const float* x  = (const float*)d_in[0];
    const float* W0 = (const float*)d_in[1];
    const float* b0 = (const float*)d_in[2];
    const float* W1 = (const float*)d_in[3];
    const float* b1 = (const float*)d_in[4];
    const float* Wr = (const float*)d_in[5];
    const float* br = (const float*)d_in[6];
    float* y = (float*)d_out;

    char* ws = (char*)d_ws;
    float*    c0  = (float*)(ws);                      // 4 MB
    float*    c1  = (float*)(ws + 4194304);            // 4 MB
    _Float16* h0a = (_Float16*)(ws + 8388608);         // 2 MB
    _Float16* h1a = (_Float16*)(ws + 10485760);        // 2 MB (+4 KB pad)
    _Float16* h0b = (_Float16*)(ws + 12587008);        // 2 MB
    _Float16* h1b = (_Float16*)(ws + 14684160);        // 2 MB
    _Float16* xh  = (_Float16*)(ws + 16781312);        // 16 MB
    _Float16* Wp0 = (_Float16*)(ws + 33558528);        // 360 KB
    _Float16* Wp1 = (_Float16*)(ws + 33927168);        // 576 KB  (total ~34.5 MB)

    // zero recurrent state read at t=0 (c0, c1, h0a, h1a)
    hipMemsetAsync(ws, 0, 12587008, stream);

    pack_w<<<dim3((184320 + 255) / 256), 256, 0, stream>>>(W0, Wp0, 5, 68, 1, 184320);
    pack_w<<<dim3((294912 + 255) / 256), 256, 0, stream>>>(W1, Wp1, 8, 128, 0, 294912);
    xconv<<<dim3(2048), 256, 0, stream>>>(x, xh);

    dim3 cgrid(128, 2);
    for (int t = 0; t < 32; ++t) {
        const _Float16* xt = xh + (size_t)t * 16384 * 16;
        _Float16* h0r = (t & 1) ? h0b : h0a;
        _Float16* h0w = (t & 1) ? h0a : h0b;
        _Float16* h1r = (t & 1) ? h1b : h1a;
        _Float16* h1w = (t & 1) ? h1a : h1b;
        cell_mfma<5, true ><<<cgrid, 256, 0, stream>>>(xt,  h0r, Wp0, b0, c0, h0w);
        cell_mfma<8, false><<<cgrid, 256, 0, stream>>>(h0w, h1r, Wp1, b1, c1, h1w);
        readout<<<64, 256, 0, stream>>>(h1w, Wr, br, y + (size_t)t * NPIX);
    }
}

// Round 3
// 1769.996 us; speedup vs baseline: 16.6590x; 1.0391x over previous
//
#include <hip/hip_runtime.h>
#include <cstdint>
#include <cmath>

#define HW 128
#define NPIX (HW * HW)

typedef _Float16 half8 __attribute__((ext_vector_type(8)));
typedef _Float16 half4 __attribute__((ext_vector_type(4)));
typedef float floatx16 __attribute__((ext_vector_type(16)));

__device__ __forceinline__ float sigf(float x) { return 1.0f / (1.0f + expf(-x)); }

// ---------------------------------------------------------------------------
// Fused ConvLSTM cell, implicit GEMM on v_mfma_f32_32x32x16_f16.
//   Block: 256 thr = 4 waves. Covers 64 gate rows (one hg: hid hg*16..+15,
//   all 4 gates) x 128 px (8x16 tile). Wave w: px rows {2w, 2w+1} x 16 cols.
//   Per wave: acc0 (gates i/f), acc1 (gates o/g); per tap-kc iter:
//   2 A frags (global, L1-shared across waves) + 1 B frag (LDS) -> 2 MFMA.
//   Grid 128 spatial x 4 hg = 512 blocks -> 2 blocks/CU co-resident.
//   LDS: [180 halo px][NCHP slots][8 halfs], linear, +1 pad slot (2-way banks).
// ---------------------------------------------------------------------------
template<int NKC, bool CELL1>
__global__ __launch_bounds__(256, 2)
void cell_mfma(const _Float16* __restrict__ srcA,   // cell1: xh_t [px][16]; cell2: h0 [px][64]
               const _Float16* __restrict__ srcB,   // h_prev of this cell [px][64]
               const _Float16* __restrict__ Wp,     // packed [NKC][9][8 mf][512]
               const float* __restrict__ bias,      // [256]
               float* __restrict__ c_io,            // [px][64] fp32, in-place
               _Float16* __restrict__ h_out)        // [px][64] fp16
{
    constexpr int NCH  = 2 * NKC;       // k-chunks actually used
    constexpr int NCHP = NCH + 1;       // +1 pad slot -> conflict-free ds_read_b128
    __shared__ __align__(16) _Float16 lds[180 * NCHP * 8];

    const int tid = threadIdx.x;
    const int ty = blockIdx.x >> 3, tx = blockIdx.x & 7;
    const int y0 = ty * 8, x0 = tx * 16;
    const int hg = blockIdx.y;          // hid group 0..3

    // ---- stage halo 10x18 px x NCH chunks (zero-padded at image borders) ----
    for (int i = tid; i < 180 * NCH; i += 256) {
        int ks, pc;
        if (NCH == 16) { ks = i & 15; pc = i >> 4; }
        else           { ks = i % NCH; pc = i / NCH; }
        int r = pc / 18, c = pc - r * 18;
        int gy = y0 - 1 + r, gx = x0 - 1 + c;
        half8 v = {0, 0, 0, 0, 0, 0, 0, 0};
        if (gy >= 0 && gy < HW && gx >= 0 && gx < HW) {
            int px = gy * HW + gx;
            if (CELL1) v = (ks < 2) ? *(const half8*)(srcA + px * 16 + ks * 8)
                                    : *(const half8*)(srcB + px * 64 + (ks - 2) * 8);
            else       v = (ks < 8) ? *(const half8*)(srcA + (size_t)px * 64 + ks * 8)
                                    : *(const half8*)(srcB + (size_t)px * 64 + (ks - 8) * 8);
        }
        *(half8*)(lds + ((size_t)pc * NCHP + ks) * 8) = v;
    }
    __syncthreads();

    const int lane = tid & 63;
    const int w    = tid >> 6;
    const int l4   = (lane >> 4) & 1;
    const int l5   = lane >> 5;
    const int xc   = lane & 15;
    const int rb   = 2 * w + l4;        // halo row base for this lane's px row

    floatx16 acc0 = {0,0,0,0,0,0,0,0,0,0,0,0,0,0,0,0};
    floatx16 acc1 = {0,0,0,0,0,0,0,0,0,0,0,0,0,0,0,0};

    const _Float16* wbase = Wp + hg * 1024 + lane * 8;

    for (int kc = 0; kc < NKC; ++kc) {
        // load all 18 A frags for this kc up front (hidden under prior MFMAs)
        half8 a[9][2];
        const _Float16* ap = wbase + (size_t)kc * 9 * 4096;
        #pragma unroll
        for (int tap = 0; tap < 9; ++tap) {
            a[tap][0] = *(const half8*)(ap + tap * 4096);
            a[tap][1] = *(const half8*)(ap + tap * 4096 + 512);
        }
        const int chunk = kc * 2 + l5;
        #pragma unroll
        for (int tap = 0; tap < 9; ++tap) {
            const int dy = tap / 3, dx = tap % 3;
            const int pc = (rb + dy) * 18 + (xc + dx);
            half8 b = *(const half8*)(lds + ((size_t)pc * NCHP + chunk) * 8);
            acc0 = __builtin_amdgcn_mfma_f32_32x32x16_f16(a[tap][0], b, acc0, 0, 0, 0);
            acc1 = __builtin_amdgcn_mfma_f32_32x32x16_f16(a[tap][1], b, acc1, 0, 0, 0);
        }
    }

    // ---- LSTM epilogue.  C/D: col = lane&31 -> px (l4, xc); row rr =
    //      (r&3) + 8*(r>>2) + 4*l5;  rr<16 -> gates i/o, rr>=16 -> f/g. ----
    const int gy = y0 + rb;
    const int gx = x0 + xc;
    const size_t pxo = (size_t)(gy * HW + gx) * 64;
    #pragma unroll
    for (int q = 0; q < 2; ++q) {
        int ch0 = hg * 16 + 4 * l5 + 8 * q;     // first of 4 hid channels
        float4 b_i4 = *(const float4*)(bias +       ch0);
        float4 b_f4 = *(const float4*)(bias +  64 + ch0);
        float4 b_o4 = *(const float4*)(bias + 128 + ch0);
        float4 b_g4 = *(const float4*)(bias + 192 + ch0);
        float bi[4] = {b_i4.x, b_i4.y, b_i4.z, b_i4.w};
        float bf[4] = {b_f4.x, b_f4.y, b_f4.z, b_f4.w};
        float bo[4] = {b_o4.x, b_o4.y, b_o4.z, b_o4.w};
        float bg[4] = {b_g4.x, b_g4.y, b_g4.z, b_g4.w};
        float4 cp4 = *(const float4*)(c_io + pxo + ch0);
        float cpv[4] = {cp4.x, cp4.y, cp4.z, cp4.w};
        float cn[4];
        half4 hn;
        #pragma unroll
        for (int lo = 0; lo < 4; ++lo) {
            int r0_ = 4 * q + lo;        // rr < 16 -> gates i (acc0) / o (acc1)
            int r1_ = 8 + 4 * q + lo;    // rr >= 16 -> gates f / g
            float iv = sigf(acc0[r0_] + bi[lo]);
            float fv = sigf(acc0[r1_] + bf[lo]);
            float ov = sigf(acc1[r0_] + bo[lo]);
            float gv = tanhf(acc1[r1_] + bg[lo]);
            float cv = fv * cpv[lo] + iv * gv;
            cn[lo] = cv;
            hn[lo] = (_Float16)(ov * tanhf(cv));
        }
        *(float4*)(c_io + pxo + ch0) = make_float4(cn[0], cn[1], cn[2], cn[3]);
        *(half4*)(h_out + pxo + ch0) = hn;
    }
}

// ---------------------------------------------------------------------------
// Weight repack: W [256][CIN_W][3][3] fp32 -> Wp [NKC][9][8 mf][64 lanes][8] fp16.
// Logical k = kc*16 + (lane>>5)*8 + j matches the cell kernel's B chunk map.
// ---------------------------------------------------------------------------
__global__ void pack_w(const float* __restrict__ W, _Float16* __restrict__ Wp,
                       int NKC, int CIN_W, int cell1, int total)
{
    int idx = blockIdx.x * 256 + threadIdx.x;
    if (idx >= total) return;
    int j  = idx & 7;
    int l  = (idx >> 3) & 63;
    int mf = (idx >> 9) & 7;
    int kt = idx >> 12;                 // kc*9 + tap
    int tap = kt % 9, kc = kt / 9;
    int rr = l & 31, l5 = l >> 5;
    int f = mf & 1, hg = mf >> 1;
    int gate = f * 2 + (rr >> 4);
    int hid  = hg * 16 + (rr & 15);
    int o = gate * 64 + hid;
    int k = kc * 16 + l5 * 8 + j;
    int cin;
    if (cell1) cin = (k < 4) ? k : ((k >= 16 && k < 80) ? (k - 12) : -1);
    else       cin = k;
    float v = (cin >= 0) ? W[((size_t)o * CIN_W + cin) * 9 + tap] : 0.0f;
    Wp[idx] = (_Float16)v;
}

// x [32][4][128][128] fp32 -> xh [32][px][16] fp16 (ch 0-3 real, 4-15 zero)
__global__ void xconv(const float* __restrict__ x, _Float16* __restrict__ xh)
{
    int idx = blockIdx.x * 256 + threadIdx.x;       // 524288
    int t = idx >> 14, px = idx & 16383;
    const float* xs = x + (size_t)t * 4 * NPIX + px;
    half8 v = {0, 0, 0, 0, 0, 0, 0, 0};
    v[0] = (_Float16)xs[0];
    v[1] = (_Float16)xs[NPIX];
    v[2] = (_Float16)xs[2 * NPIX];
    v[3] = (_Float16)xs[3 * NPIX];
    half8 z = {0, 0, 0, 0, 0, 0, 0, 0};
    *(half8*)(xh + (size_t)idx * 16)     = v;
    *(half8*)(xh + (size_t)idx * 16 + 8) = z;
}

// Readout conv 64->1, one px per thread; h1 is fp16 [px][64]. 256 blocks x 64 thr.
__global__ __launch_bounds__(64)
void readout(const _Float16* __restrict__ h1, const float* __restrict__ Wr,
             const float* __restrict__ br, float* __restrict__ y)
{
    __shared__ float wl[576];
    int tid = threadIdx.x;
    for (int i = tid; i < 576; i += 64) wl[i] = Wr[i];
    __syncthreads();
    int px = blockIdx.x * 64 + tid;
    int py = px >> 7, pxx = px & 127;
    float s = br[0];
    #pragma unroll
    for (int dy = -1; dy <= 1; ++dy) {
        int gy = py + dy;
        if (gy < 0 || gy >= HW) continue;
        #pragma unroll
        for (int dx = -1; dx <= 1; ++dx) {
            int gx = pxx + dx;
            if (gx < 0 || gx >= HW) continue;
            const _Float16* hp = h1 + (size_t)(gy * HW + gx) * 64;
            int tap = (dy + 1) * 3 + (dx + 1);
            #pragma unroll
            for (int dc = 0; dc < 64; dc += 8) {
                half8 hv = *(const half8*)(hp + dc);
                #pragma unroll
                for (int jj = 0; jj < 8; ++jj)
                    s += wl[(dc + jj) * 9 + tap] * (float)hv[jj];
            }
        }
    }
    y[px] = s;
}

extern "C" void kernel_launch(void* const* d_in, const int* in_sizes, int n_in,
                              void* d_out, int out_size, void* d_ws, size_t ws_size,
                              hipStream_t stream)
{
    const float* x  = (const float*)d_in[0];
    const float* W0 = (const float*)d_in[1];
    const float* b0 = (const float*)d_in[2];
    const float* W1 = (const float*)d_in[3];
    const float* b1 = (const float*)d_in[4];
    const float* Wr = (const float*)d_in[5];
    const float* br = (const float*)d_in[6];
    float* y = (float*)d_out;

    char* ws = (char*)d_ws;
    float*    c0  = (float*)(ws);                       // 4 MB
    float*    c1  = (float*)(ws + (4u << 20));          // 4 MB
    _Float16* h0a = (_Float16*)(ws + (8u << 20));       // 2 MB
    _Float16* h1a = (_Float16*)(ws + (10u << 20));      // 2 MB
    _Float16* h0b = (_Float16*)(ws + (12u << 20));      // 2 MB
    _Float16* h1b = (_Float16*)(ws + (14u << 20));      // 2 MB
    _Float16* xh  = (_Float16*)(ws + (16u << 20));      // 16 MB
    _Float16* Wp0 = (_Float16*)(ws + (32u << 20));      // 360 KB
    _Float16* Wp1 = (_Float16*)(ws + (33u << 20));      // 576 KB

    // zero recurrent state read at t=0 (c0, c1, h0a, h1a)
    hipMemsetAsync(ws, 0, (12u << 20), stream);

    pack_w<<<dim3((184320 + 255) / 256), 256, 0, stream>>>(W0, Wp0, 5, 68, 1, 184320);
    pack_w<<<dim3((294912 + 255) / 256), 256, 0, stream>>>(W1, Wp1, 8, 128, 0, 294912);
    xconv<<<dim3(2048), 256, 0, stream>>>(x, xh);

    dim3 cgrid(128, 4);
    for (int t = 0; t < 32; ++t) {
        const _Float16* xt = xh + (size_t)t * 16384 * 16;
        _Float16* h0r = (t & 1) ? h0b : h0a;
        _Float16* h0w = (t & 1) ? h0a : h0b;
        _Float16* h1r = (t & 1) ? h1b : h1a;
        _Float16* h1w = (t & 1) ? h1a : h1b;
        cell_mfma<5, true ><<<cgrid, 256, 0, stream>>>(xt,  h0r, Wp0, b0, c0, h0w);
        cell_mfma<8, false><<<cgrid, 256, 0, stream>>>(h0w, h1r, Wp1, b1, c1, h1w);
        readout<<<256, 64, 0, stream>>>(h1w, Wr, br, y + (size_t)t * NPIX);
    }
}